// Round 1
// baseline (659.956 us; speedup 1.0000x reference)
//
#include <hip/hip_runtime.h>
#include <hip/hip_bf16.h>

// ---------------------------------------------------------------------------
// NanoGPT block on MI355X (gfx950). bf16 MFMA GEMMs, fp32 accumulate.
// Round 5: operand-swapped epilogues. MFMA C/D layout puts the 4 acc regs on
// 4 consecutive ROWS (col=lane&15, row=quad*4+reg), so every GEMM is computed
// with the output's contiguous dim as the A(row) operand:
//   QK^T: mfma(K,Q)  -> P[q][k] packed 8B stores + cheap rowsum (2 shfl/j)
//   PV:   mfma(Vt,P) -> O[q][d] packed 8B stores, m-fast XCD swizzle
//   QKV z=2: mfma(Wv,y1) -> Vt written coalesced (was stride-32KB scatter)
//   MLP:  mfma(W,act) -> h packed 8B bf16, out packed float4 + float4 resid
// exp uses exp2f with scale pre-multiplied by log2(e). P/out stores are
// non-temporal (never re-read from cache).
// ---------------------------------------------------------------------------

#define DDIM 768
#define TT   4096
#define NB   4
#define ROWS (NB * TT)   // 16384

using bf16 = __hip_bfloat16;
typedef __bf16 bf16x8 __attribute__((ext_vector_type(8)));
typedef float  f32x4  __attribute__((ext_vector_type(4)));
typedef unsigned short us4 __attribute__((ext_vector_type(4)));

__device__ __forceinline__ float to_f(float x) { return x; }
__device__ __forceinline__ float to_f(bf16 x) { return __bfloat162float(x); }

__device__ __forceinline__ unsigned short bfb(float f) {
  bf16 b = __float2bfloat16(f);
  return __builtin_bit_cast(unsigned short, b);
}

// Async global->LDS, 16B per lane. LDS dest is wave-uniform base + lane*16.
__device__ __forceinline__ void gload16(const void* g, void* l) {
#if __has_builtin(__builtin_amdgcn_global_load_lds)
  __builtin_amdgcn_global_load_lds(
      (const __attribute__((address_space(1))) void*)g,
      (__attribute__((address_space(3))) void*)l, 16, 0, 0);
#else
  int lane = threadIdx.x & 63;
  ((int4*)l)[lane] = *(const int4*)g;
#endif
}

// ---------------------------------------------------------------------------
// Generic batched GEMM: C[z] = A[z][M x K] * B[z][N x K]^T  (bf16 in)
// 128x128 tile per block, 256 threads = 4 waves, each wave 64x64 (4x4 MFMA).
// acc layout: rows (M dim) = quad*4+reg (4 consecutive), cols (N dim)=lane&15.
// All epilogues store OUTPUT[col][row] so the 4 regs pack into one 8B store.
// SWZ: 0 = plain 3D grid; 1 = n-fastest XCD swizzle (group=(m,z) pinned);
//      2 = m-fastest XCD swizzle (group=(n,z) pinned).
// MODE 3: h[col][row] = relu(acc + bias[row]), bf16
// MODE 4: out[col][row] = acc + bias[row] + resid[col][row], fp32 (float4, nt)
// MODE 5: P[col][row] = exp2(acc*scale) bf16 (nt), row sums over M -> Lsum[col]
// MODE 6: O[col][row] = acc / Lsum[col], bf16
// ---------------------------------------------------------------------------
template <int MODE, int SWZ, int NT, int MT>
__global__ __launch_bounds__(256) void gemm_bt(
    const bf16* __restrict__ A, int lda, long sA,
    const bf16* __restrict__ B, int ldb, long sB,
    void* __restrict__ Cout, int ldc, long sC, int K, float scale,
    const float* __restrict__ bias, const float* __restrict__ resid,
    float* __restrict__ Lsum) {
  __shared__ __align__(16) bf16 As[128 * 32];
  __shared__ __align__(16) bf16 Bs[128 * 32];
  __shared__ float Lred[128];

  int bx, by, bz;
  if constexpr (SWZ == 1) {
    const int h   = blockIdx.x;
    const int xcd = h & 7;
    const int s   = h >> 3;
    bx = s % NT;                           // n cycles fastest within an XCD
    const int g = (s / NT) * 8 + xcd;      // (m,z) group pinned to this XCD
    by = g % MT;
    bz = g / MT;
  } else if constexpr (SWZ == 2) {
    const int h   = blockIdx.x;
    const int xcd = h & 7;
    const int s   = h >> 3;
    by = s % MT;                           // m cycles fastest within an XCD
    const int g = (s / MT) * 8 + xcd;      // (n,z) group pinned to this XCD
    bx = g % NT;
    bz = g / NT;
  } else {
    bx = blockIdx.x; by = blockIdx.y; bz = blockIdx.z;
  }

  A += (long)bz * sA;
  B += (long)bz * sB;

  const int tid  = threadIdx.x;
  const int wave = tid >> 6;
  const int lane = tid & 63;
  const int l16  = lane & 15;
  const int lq   = lane >> 4;          // quad 0..3
  const int wm   = wave >> 1;          // wave row 0..1
  const int wn   = wave & 1;           // wave col 0..1
  const long tileM = (long)by * 128;
  const long tileN = (long)bx * 128;

  if constexpr (MODE == 5) {
    if (tid < 128) Lred[tid] = 0.f;
  }

  f32x4 acc[4][4] = {};

  const int c0 = wave * 128 + lane;
  const int c1 = c0 + 64;
  bf16* ldsA0 = &As[(wave * 128 + 0) * 8];
  bf16* ldsA1 = &As[(wave * 128 + 64) * 8];
  bf16* ldsB0 = &Bs[(wave * 128 + 0) * 8];
  bf16* ldsB1 = &Bs[(wave * 128 + 64) * 8];
  const long ar0 = (tileM + (c0 >> 2)) * (long)lda + (c0 & 3) * 8;
  const long ar1 = (tileM + (c1 >> 2)) * (long)lda + (c1 & 3) * 8;
  const long br0 = (tileN + (c0 >> 2)) * (long)ldb + (c0 & 3) * 8;
  const long br1 = (tileN + (c1 >> 2)) * (long)ldb + (c1 & 3) * 8;

  for (int k0 = 0; k0 < K; k0 += 32) {
    gload16(A + ar0 + k0, ldsA0);
    gload16(A + ar1 + k0, ldsA1);
    gload16(B + br0 + k0, ldsB0);
    gload16(B + br1 + k0, ldsB1);
    __syncthreads();

    bf16x8 af[4], bf_[4];
#pragma unroll
    for (int i = 0; i < 4; ++i)
      af[i] = *(const bf16x8*)&As[(wm * 64 + i * 16 + l16) * 32 + lq * 8];
#pragma unroll
    for (int j = 0; j < 4; ++j)
      bf_[j] = *(const bf16x8*)&Bs[(wn * 64 + j * 16 + l16) * 32 + lq * 8];
#pragma unroll
    for (int i = 0; i < 4; ++i)
#pragma unroll
      for (int j = 0; j < 4; ++j)
        acc[i][j] = __builtin_amdgcn_mfma_f32_16x16x32_bf16(af[i], bf_[j],
                                                            acc[i][j], 0, 0, 0);
    __syncthreads();
  }

  const long base_m = tileM + wm * 64;   // acc row dim (A rows)
  const long base_n = tileN + wn * 64;   // acc col dim (B rows)

  if constexpr (MODE == 5) {
    // A=K-matrix (rows=k), B=Q (rows=q). P[q][k], rowsum over k per q.
    bf16* P = (bf16*)Cout + (long)bz * sC;
    float ps[4] = {0.f, 0.f, 0.f, 0.f};
#pragma unroll
    for (int j = 0; j < 4; ++j) {
      const long colq = base_n + j * 16 + l16;
#pragma unroll
      for (int i = 0; i < 4; ++i) {
        const long krow = base_m + i * 16 + lq * 4;
        const float p0 = exp2f(acc[i][j][0] * scale);
        const float p1 = exp2f(acc[i][j][1] * scale);
        const float p2 = exp2f(acc[i][j][2] * scale);
        const float p3 = exp2f(acc[i][j][3] * scale);
        ps[j] += (p0 + p1) + (p2 + p3);
        us4 w = {bfb(p0), bfb(p1), bfb(p2), bfb(p3)};
        __builtin_nontemporal_store(w, (us4*)(P + colq * (long)ldc + krow));
      }
    }
    // reduce partial sums over the quad dim (lanes 16,32 apart share l16)
#pragma unroll
    for (int j = 0; j < 4; ++j) {
      float v = ps[j];
      v += __shfl_xor(v, 16);
      v += __shfl_xor(v, 32);
      if (lq == 0) atomicAdd(&Lred[wn * 64 + j * 16 + l16], v);
    }
    __syncthreads();
    if (tid < 128) atomicAdd(&Lsum[(long)bz * TT + tileN + tid], Lred[tid]);
  } else if constexpr (MODE == 6) {
    // A=Vt (rows=d), B=P (rows=q). O[q][d] = acc / Lsum[q].
    bf16* Op = (bf16*)Cout + (long)bz * sC;
    float inv[4];
#pragma unroll
    for (int j = 0; j < 4; ++j)
      inv[j] = 1.0f / Lsum[(long)bz * TT + base_n + j * 16 + l16];
#pragma unroll
    for (int j = 0; j < 4; ++j) {
      const long colq = base_n + j * 16 + l16;
#pragma unroll
      for (int i = 0; i < 4; ++i) {
        const long drow = base_m + i * 16 + lq * 4;
        us4 w = {bfb(acc[i][j][0] * inv[j]), bfb(acc[i][j][1] * inv[j]),
                 bfb(acc[i][j][2] * inv[j]), bfb(acc[i][j][3] * inv[j])};
        *(us4*)(Op + colq * (long)ldc + drow) = w;
      }
    }
  } else if constexpr (MODE == 3) {
    // A=W (rows=out_d), B=activations (rows=token). h[tok][d]=relu(acc+b[d])
    bf16* Hp = (bf16*)Cout;
#pragma unroll
    for (int i = 0; i < 4; ++i) {
      const long drow = base_m + i * 16 + lq * 4;
      const f32x4 bv = *(const f32x4*)&bias[drow];
#pragma unroll
      for (int j = 0; j < 4; ++j) {
        const long colt = base_n + j * 16 + l16;
        float v0 = acc[i][j][0] + bv[0]; v0 = v0 > 0.f ? v0 : 0.f;
        float v1 = acc[i][j][1] + bv[1]; v1 = v1 > 0.f ? v1 : 0.f;
        float v2 = acc[i][j][2] + bv[2]; v2 = v2 > 0.f ? v2 : 0.f;
        float v3 = acc[i][j][3] + bv[3]; v3 = v3 > 0.f ? v3 : 0.f;
        us4 w = {bfb(v0), bfb(v1), bfb(v2), bfb(v3)};
        *(us4*)(Hp + colt * (long)ldc + drow) = w;
      }
    }
  } else {  // MODE 4
    // out[tok][d] = acc + bias[d] + resid[tok][d], fp32, float4 stores (nt)
    float* Op = (float*)Cout;
#pragma unroll
    for (int i = 0; i < 4; ++i) {
      const long drow = base_m + i * 16 + lq * 4;
      const f32x4 bv = *(const f32x4*)&bias[drow];
#pragma unroll
      for (int j = 0; j < 4; ++j) {
        const long off = (base_n + j * 16 + l16) * (long)ldc + drow;
        const f32x4 rs = *(const f32x4*)&resid[off];
        f32x4 o;
        o[0] = acc[i][j][0] + bv[0] + rs[0];
        o[1] = acc[i][j][1] + bv[1] + rs[1];
        o[2] = acc[i][j][2] + bv[2] + rs[2];
        o[3] = acc[i][j][3] + bv[3] + rs[3];
        __builtin_nontemporal_store(o, (f32x4*)(Op + off));
      }
    }
  }
}

// ---------------------------------------------------------------------------
// Fused QKV projection: grid.z selects {Q, K, V}. z=0,1: A=y1 (rows=token),
// B=W, plain store to Qm/Km. z=2: OPERANDS SWAPPED (A=Wv rows=out_d, B=y1)
// so Vt[d][tok] is written with tok as the lane-contiguous dim (coalesced).
// ---------------------------------------------------------------------------
__global__ __launch_bounds__(256) void gemm_qkv(
    const bf16* __restrict__ Y,
    const bf16* __restrict__ Wq, const bf16* __restrict__ Wk,
    const bf16* __restrict__ Wv, bf16* __restrict__ Qm,
    bf16* __restrict__ Km, bf16* __restrict__ Vt) {
  __shared__ __align__(16) bf16 As[128 * 32];
  __shared__ __align__(16) bf16 Bs[128 * 32];

  const int z = blockIdx.z;
  const bf16* Ap = (z == 2) ? Wv : Y;
  const bf16* Bp = (z == 0) ? Wq : (z == 1) ? Wk : Y;

  const int tid  = threadIdx.x;
  const int wave = tid >> 6;
  const int lane = tid & 63;
  const int l16  = lane & 15;
  const int lq   = lane >> 4;
  const int wm   = wave >> 1;
  const int wn   = wave & 1;
  const long tileM = (z == 2) ? (long)blockIdx.x * 128 : (long)blockIdx.y * 128;
  const long tileN = (z == 2) ? (long)blockIdx.y * 128 : (long)blockIdx.x * 128;

  f32x4 acc[4][4] = {};

  const int c0 = wave * 128 + lane;
  const int c1 = c0 + 64;
  bf16* ldsA0 = &As[(wave * 128 + 0) * 8];
  bf16* ldsA1 = &As[(wave * 128 + 64) * 8];
  bf16* ldsB0 = &Bs[(wave * 128 + 0) * 8];
  bf16* ldsB1 = &Bs[(wave * 128 + 64) * 8];
  const long ar0 = (tileM + (c0 >> 2)) * (long)DDIM + (c0 & 3) * 8;
  const long ar1 = (tileM + (c1 >> 2)) * (long)DDIM + (c1 & 3) * 8;
  const long br0 = (tileN + (c0 >> 2)) * (long)DDIM + (c0 & 3) * 8;
  const long br1 = (tileN + (c1 >> 2)) * (long)DDIM + (c1 & 3) * 8;

  for (int k0 = 0; k0 < DDIM; k0 += 32) {
    gload16(Ap + ar0 + k0, ldsA0);
    gload16(Ap + ar1 + k0, ldsA1);
    gload16(Bp + br0 + k0, ldsB0);
    gload16(Bp + br1 + k0, ldsB1);
    __syncthreads();

    bf16x8 af[4], bf_[4];
#pragma unroll
    for (int i = 0; i < 4; ++i)
      af[i] = *(const bf16x8*)&As[(wm * 64 + i * 16 + l16) * 32 + lq * 8];
#pragma unroll
    for (int j = 0; j < 4; ++j)
      bf_[j] = *(const bf16x8*)&Bs[(wn * 64 + j * 16 + l16) * 32 + lq * 8];
#pragma unroll
    for (int i = 0; i < 4; ++i)
#pragma unroll
      for (int j = 0; j < 4; ++j)
        acc[i][j] = __builtin_amdgcn_mfma_f32_16x16x32_bf16(af[i], bf_[j],
                                                            acc[i][j], 0, 0, 0);
    __syncthreads();
  }

  const long base_m = tileM + wm * 64;
  const long base_n = tileN + wn * 64;
  bf16* Cp = (z == 0) ? Qm : (z == 1) ? Km : Vt;
  const long ldo = (z < 2) ? (long)DDIM : (long)ROWS;
#pragma unroll
  for (int i = 0; i < 4; ++i)
#pragma unroll
    for (int j = 0; j < 4; ++j)
#pragma unroll
      for (int r = 0; r < 4; ++r) {
        const long row = base_m + i * 16 + lq * 4 + r;
        const long col = base_n + j * 16 + l16;
        Cp[row * ldo + col] = __float2bfloat16(acc[i][j][r]);
      }
}

// ---------------------------------------------------------------------------
// LayerNorm (faithful to buggy reference): y = (x - mu/sqrt(var)) * g + b,
// var unbiased (ddof=1). One block (256 thr) per 768-element row. Out bf16.
// Optionally zeroes Lzero[row] (the attention row-sum accumulator).
// ---------------------------------------------------------------------------
template <typename T>
__global__ __launch_bounds__(256) void ln_kernel(
    const T* __restrict__ in, const float* __restrict__ g,
    const float* __restrict__ beta, bf16* __restrict__ out,
    float* __restrict__ Lzero) {
  const long row = blockIdx.x;
  if (Lzero != nullptr && threadIdx.x == 0) Lzero[row] = 0.f;
  const T* xr = in + row * DDIM;
  const int t = threadIdx.x;
  float v0 = to_f(xr[t]), v1 = to_f(xr[t + 256]), v2 = to_f(xr[t + 512]);
  float s = v0 + v1 + v2;
  float q = v0 * v0 + v1 * v1 + v2 * v2;
#pragma unroll
  for (int o = 32; o; o >>= 1) {
    s += __shfl_down(s, o);
    q += __shfl_down(q, o);
  }
  __shared__ float sb[4], qb[4];
  if ((t & 63) == 0) { sb[t >> 6] = s; qb[t >> 6] = q; }
  __syncthreads();
  const float S = sb[0] + sb[1] + sb[2] + sb[3];
  const float Q = qb[0] + qb[1] + qb[2] + qb[3];
  const float mu  = S * (1.0f / 768.0f);
  const float var = (Q - 768.0f * mu * mu) * (1.0f / 767.0f);
  const float sub = mu / sqrtf(var);
  bf16* orow = out + row * DDIM;
  orow[t]       = __float2bfloat16((v0 - sub) * g[t]       + beta[t]);
  orow[t + 256] = __float2bfloat16((v1 - sub) * g[t + 256] + beta[t + 256]);
  orow[t + 512] = __float2bfloat16((v2 - sub) * g[t + 512] + beta[t + 512]);
}

// ---------------------------------------------------------------------------
// Weight prep: z=0..2 transpose+cast wq/wk/wv (K x N -> N x K bf16),
// z=3..4 straight cast fc1_w/fc2_w (already N x K).
// block (32,8), grid (24,24,5)
// ---------------------------------------------------------------------------
__global__ void prep_weights(const float* __restrict__ wq,
                             const float* __restrict__ wk,
                             const float* __restrict__ wv,
                             const float* __restrict__ f1,
                             const float* __restrict__ f2,
                             bf16* wqt, bf16* wkt, bf16* wvt, bf16* f1b,
                             bf16* f2b) {
  __shared__ float tile[32][33];
  const float* src;
  bf16* dst;
  bool tr = true;
  switch (blockIdx.z) {
    case 0: src = wq; dst = wqt; break;
    case 1: src = wk; dst = wkt; break;
    case 2: src = wv; dst = wvt; break;
    case 3: src = f1; dst = f1b; tr = false; break;
    default: src = f2; dst = f2b; tr = false; break;
  }
  const int tx = threadIdx.x, ty = threadIdx.y;
  const int x = blockIdx.x * 32 + tx;
  const int y = blockIdx.y * 32 + ty;
  if (tr) {
#pragma unroll
    for (int r = 0; r < 4; ++r) tile[ty + 8 * r][tx] = src[(y + 8 * r) * DDIM + x];
    __syncthreads();
    const int ox = blockIdx.y * 32 + tx;
    const int oy = blockIdx.x * 32 + ty;
#pragma unroll
    for (int r = 0; r < 4; ++r)
      dst[(oy + 8 * r) * DDIM + ox] = __float2bfloat16(tile[tx][ty + 8 * r]);
  } else {
#pragma unroll
    for (int r = 0; r < 4; ++r)
      dst[(y + 8 * r) * DDIM + x] = __float2bfloat16(src[(y + 8 * r) * DDIM + x]);
  }
}

// ---------------------------------------------------------------------------
extern "C" void kernel_launch(void* const* d_in, const int* in_sizes, int n_in,
                              void* d_out, int out_size, void* d_ws,
                              size_t ws_size, hipStream_t stream) {
  const float* x     = (const float*)d_in[0];
  const float* ln1_g = (const float*)d_in[1];
  const float* ln1_b = (const float*)d_in[2];
  const float* wq    = (const float*)d_in[3];
  const float* wk    = (const float*)d_in[4];
  const float* wv    = (const float*)d_in[5];
  const float* ln2_g = (const float*)d_in[6];
  const float* ln2_b = (const float*)d_in[7];
  const float* f1w   = (const float*)d_in[8];
  const float* f1bias= (const float*)d_in[9];
  const float* f2w   = (const float*)d_in[10];
  const float* f2bias= (const float*)d_in[11];
  float* out = (float*)d_out;

  char* ws = (char*)d_ws;
  size_t off = 0;
  auto take = [&](size_t bytes) -> char* {
    char* p = ws + off;
    off += (bytes + 255) & ~(size_t)255;
    return p;
  };
  const size_t WB = (size_t)DDIM * DDIM * sizeof(bf16);   // 1.18 MB
  const size_t MB = (size_t)ROWS * DDIM * sizeof(bf16);   // 25.2 MB
  bf16* wqt = (bf16*)take(WB);
  bf16* wkt = (bf16*)take(WB);
  bf16* wvt = (bf16*)take(WB);
  bf16* f1b = (bf16*)take(WB);
  bf16* f2b = (bf16*)take(WB);
  float* Lsum = (float*)take((size_t)ROWS * sizeof(float));  // softmax row sums
  bf16* y1  = (bf16*)take(MB);
  bf16* Qm  = (bf16*)take(MB);
  bf16* Km  = (bf16*)take(MB);
  bf16* Vt  = (bf16*)take(MB);                              // V^T: 768 x 16384
  bf16* Sb  = (bf16*)take((size_t)NB * TT * TT * sizeof(bf16));  // 134 MB (P)
  // buffer reuse (strictly sequential stream):
  bf16* O  = y1;  // attention output (y1 dead after QKV)
  bf16* y2 = Qm;  // LN2 output      (Q dead after QK^T)
  bf16* h  = Km;  // MLP hidden      (K dead after QK^T)

  prep_weights<<<dim3(24, 24, 5), dim3(32, 8), 0, stream>>>(
      wq, wk, wv, f1w, f2w, wqt, wkt, wvt, f1b, f2b);

  // LN1 also zeroes Lsum (must precede QK^T; ws is re-poisoned every call)
  ln_kernel<float><<<ROWS, 256, 0, stream>>>(x, ln1_g, ln1_b, y1, Lsum);

  // Fused QKV projections, 2304 blocks (z=2 operand-swapped for Vt)
  gemm_qkv<<<dim3(6, 128, 3), 256, 0, stream>>>(y1, wqt, wkt, wvt, Qm, Km, Vt);

  // scale folded with log2(e): P = exp2(log2e/sqrt(768) * K Q^T)
  const float scale2 = 0.03608439182435161f * 1.4426950408889634f;
  // SWAPPED: A=K (rows=k), B=Q (rows=q). P[q][k] + row sums -> Lsum.
  gemm_bt<5, 1, 32, 32><<<dim3(32 * 32 * NB), 256, 0, stream>>>(
      Km, DDIM, (long)TT * DDIM, Qm, DDIM, (long)TT * DDIM, Sb, TT,
      (long)TT * TT, DDIM, scale2, nullptr, nullptr, Lsum);

  // SWAPPED: A=Vt (rows=d, k-contig per batch via sA=TT), B=P (rows=q).
  // m-fastest swizzle: P q-tile pinned per XCD group, Vt d-tiles cycle.
  gemm_bt<6, 2, 32, 6><<<dim3(6 * 32 * NB), 256, 0, stream>>>(
      Vt, ROWS, (long)TT, Sb, TT, (long)TT * TT, O, DDIM, (long)TT * DDIM, TT,
      1.f, nullptr, nullptr, Lsum);

  ln_kernel<bf16><<<ROWS, 256, 0, stream>>>(O, ln2_g, ln2_b, y2, nullptr);

  // MLP, SWAPPED (A=weight rows=out_d, B=activation rows=token).
  // m-fastest swizzle: activation tile pinned in L2, weight tiles cycle.
  gemm_bt<3, 2, 128, 6><<<dim3(128 * 6), 256, 0, stream>>>(
      f1b, DDIM, 0, y2, DDIM, 0, h, DDIM, 0, DDIM, 1.f, f1bias, nullptr,
      nullptr);
  gemm_bt<4, 2, 128, 6><<<dim3(128 * 6), 256, 0, stream>>>(
      f2b, DDIM, 0, h, DDIM, 0, out, DDIM, 0, DDIM, 1.f, f2bias, x, nullptr);
}

// Round 2
// 622.785 us; speedup vs baseline: 1.0597x; 1.0597x over previous
//
#include <hip/hip_runtime.h>
#include <hip/hip_bf16.h>

// ---------------------------------------------------------------------------
// NanoGPT block on MI355X (gfx950). bf16 MFMA GEMMs, fp32 accumulate.
// Round 6: round-5 operand-swapped epilogues, minus the P nontemporal store.
// nt on 32B-per-row partial-line stores defeated L2 write combining and
// doubled P write traffic (133->291 MB, +25us). Plain stores restore 1.0x.
// MODE 4 keeps nt (full 64B lines per instruction).
// ---------------------------------------------------------------------------

#define DDIM 768
#define TT   4096
#define NB   4
#define ROWS (NB * TT)   // 16384

using bf16 = __hip_bfloat16;
typedef __bf16 bf16x8 __attribute__((ext_vector_type(8)));
typedef float  f32x4  __attribute__((ext_vector_type(4)));
typedef unsigned short us4 __attribute__((ext_vector_type(4)));

__device__ __forceinline__ float to_f(float x) { return x; }
__device__ __forceinline__ float to_f(bf16 x) { return __bfloat162float(x); }

__device__ __forceinline__ unsigned short bfb(float f) {
  bf16 b = __float2bfloat16(f);
  return __builtin_bit_cast(unsigned short, b);
}

// Async global->LDS, 16B per lane. LDS dest is wave-uniform base + lane*16.
__device__ __forceinline__ void gload16(const void* g, void* l) {
#if __has_builtin(__builtin_amdgcn_global_load_lds)
  __builtin_amdgcn_global_load_lds(
      (const __attribute__((address_space(1))) void*)g,
      (__attribute__((address_space(3))) void*)l, 16, 0, 0);
#else
  int lane = threadIdx.x & 63;
  ((int4*)l)[lane] = *(const int4*)g;
#endif
}

// ---------------------------------------------------------------------------
// Generic batched GEMM: C[z] = A[z][M x K] * B[z][N x K]^T  (bf16 in)
// 128x128 tile per block, 256 threads = 4 waves, each wave 64x64 (4x4 MFMA).
// acc layout: rows (M dim) = quad*4+reg (4 consecutive), cols (N dim)=lane&15.
// All epilogues store OUTPUT[col][row] so the 4 regs pack into one 8B store.
// SWZ: 0 = plain 3D grid; 1 = n-fastest XCD swizzle (group=(m,z) pinned);
//      2 = m-fastest XCD swizzle (group=(n,z) pinned).
// MODE 3: h[col][row] = relu(acc + bias[row]), bf16
// MODE 4: out[col][row] = acc + bias[row] + resid[col][row], fp32 (float4, nt)
// MODE 5: P[col][row] = exp2(acc*scale) bf16, row sums over M -> Lsum[col]
// MODE 6: O[col][row] = acc / Lsum[col], bf16
// ---------------------------------------------------------------------------
template <int MODE, int SWZ, int NT, int MT>
__global__ __launch_bounds__(256) void gemm_bt(
    const bf16* __restrict__ A, int lda, long sA,
    const bf16* __restrict__ B, int ldb, long sB,
    void* __restrict__ Cout, int ldc, long sC, int K, float scale,
    const float* __restrict__ bias, const float* __restrict__ resid,
    float* __restrict__ Lsum) {
  __shared__ __align__(16) bf16 As[128 * 32];
  __shared__ __align__(16) bf16 Bs[128 * 32];
  __shared__ float Lred[128];

  int bx, by, bz;
  if constexpr (SWZ == 1) {
    const int h   = blockIdx.x;
    const int xcd = h & 7;
    const int s   = h >> 3;
    bx = s % NT;                           // n cycles fastest within an XCD
    const int g = (s / NT) * 8 + xcd;      // (m,z) group pinned to this XCD
    by = g % MT;
    bz = g / MT;
  } else if constexpr (SWZ == 2) {
    const int h   = blockIdx.x;
    const int xcd = h & 7;
    const int s   = h >> 3;
    by = s % MT;                           // m cycles fastest within an XCD
    const int g = (s / MT) * 8 + xcd;      // (n,z) group pinned to this XCD
    bx = g % NT;
    bz = g / NT;
  } else {
    bx = blockIdx.x; by = blockIdx.y; bz = blockIdx.z;
  }

  A += (long)bz * sA;
  B += (long)bz * sB;

  const int tid  = threadIdx.x;
  const int wave = tid >> 6;
  const int lane = tid & 63;
  const int l16  = lane & 15;
  const int lq   = lane >> 4;          // quad 0..3
  const int wm   = wave >> 1;          // wave row 0..1
  const int wn   = wave & 1;           // wave col 0..1
  const long tileM = (long)by * 128;
  const long tileN = (long)bx * 128;

  if constexpr (MODE == 5) {
    if (tid < 128) Lred[tid] = 0.f;
  }

  f32x4 acc[4][4] = {};

  const int c0 = wave * 128 + lane;
  const int c1 = c0 + 64;
  bf16* ldsA0 = &As[(wave * 128 + 0) * 8];
  bf16* ldsA1 = &As[(wave * 128 + 64) * 8];
  bf16* ldsB0 = &Bs[(wave * 128 + 0) * 8];
  bf16* ldsB1 = &Bs[(wave * 128 + 64) * 8];
  const long ar0 = (tileM + (c0 >> 2)) * (long)lda + (c0 & 3) * 8;
  const long ar1 = (tileM + (c1 >> 2)) * (long)lda + (c1 & 3) * 8;
  const long br0 = (tileN + (c0 >> 2)) * (long)ldb + (c0 & 3) * 8;
  const long br1 = (tileN + (c1 >> 2)) * (long)ldb + (c1 & 3) * 8;

  for (int k0 = 0; k0 < K; k0 += 32) {
    gload16(A + ar0 + k0, ldsA0);
    gload16(A + ar1 + k0, ldsA1);
    gload16(B + br0 + k0, ldsB0);
    gload16(B + br1 + k0, ldsB1);
    __syncthreads();

    bf16x8 af[4], bf_[4];
#pragma unroll
    for (int i = 0; i < 4; ++i)
      af[i] = *(const bf16x8*)&As[(wm * 64 + i * 16 + l16) * 32 + lq * 8];
#pragma unroll
    for (int j = 0; j < 4; ++j)
      bf_[j] = *(const bf16x8*)&Bs[(wn * 64 + j * 16 + l16) * 32 + lq * 8];
#pragma unroll
    for (int i = 0; i < 4; ++i)
#pragma unroll
      for (int j = 0; j < 4; ++j)
        acc[i][j] = __builtin_amdgcn_mfma_f32_16x16x32_bf16(af[i], bf_[j],
                                                            acc[i][j], 0, 0, 0);
    __syncthreads();
  }

  const long base_m = tileM + wm * 64;   // acc row dim (A rows)
  const long base_n = tileN + wn * 64;   // acc col dim (B rows)

  if constexpr (MODE == 5) {
    // A=K-matrix (rows=k), B=Q (rows=q). P[q][k], rowsum over k per q.
    bf16* P = (bf16*)Cout + (long)bz * sC;
    float ps[4] = {0.f, 0.f, 0.f, 0.f};
#pragma unroll
    for (int j = 0; j < 4; ++j) {
      const long colq = base_n + j * 16 + l16;
#pragma unroll
      for (int i = 0; i < 4; ++i) {
        const long krow = base_m + i * 16 + lq * 4;
        const float p0 = exp2f(acc[i][j][0] * scale);
        const float p1 = exp2f(acc[i][j][1] * scale);
        const float p2 = exp2f(acc[i][j][2] * scale);
        const float p3 = exp2f(acc[i][j][3] * scale);
        ps[j] += (p0 + p1) + (p2 + p3);
        us4 w = {bfb(p0), bfb(p1), bfb(p2), bfb(p3)};
        *(us4*)(P + colq * (long)ldc + krow) = w;   // plain: L2 combines lines
      }
    }
    // reduce partial sums over the quad dim (lanes 16,32 apart share l16)
#pragma unroll
    for (int j = 0; j < 4; ++j) {
      float v = ps[j];
      v += __shfl_xor(v, 16);
      v += __shfl_xor(v, 32);
      if (lq == 0) atomicAdd(&Lred[wn * 64 + j * 16 + l16], v);
    }
    __syncthreads();
    if (tid < 128) atomicAdd(&Lsum[(long)bz * TT + tileN + tid], Lred[tid]);
  } else if constexpr (MODE == 6) {
    // A=Vt (rows=d), B=P (rows=q). O[q][d] = acc / Lsum[q].
    bf16* Op = (bf16*)Cout + (long)bz * sC;
    float inv[4];
#pragma unroll
    for (int j = 0; j < 4; ++j)
      inv[j] = 1.0f / Lsum[(long)bz * TT + base_n + j * 16 + l16];
#pragma unroll
    for (int j = 0; j < 4; ++j) {
      const long colq = base_n + j * 16 + l16;
#pragma unroll
      for (int i = 0; i < 4; ++i) {
        const long drow = base_m + i * 16 + lq * 4;
        us4 w = {bfb(acc[i][j][0] * inv[j]), bfb(acc[i][j][1] * inv[j]),
                 bfb(acc[i][j][2] * inv[j]), bfb(acc[i][j][3] * inv[j])};
        *(us4*)(Op + colq * (long)ldc + drow) = w;
      }
    }
  } else if constexpr (MODE == 3) {
    // A=W (rows=out_d), B=activations (rows=token). h[tok][d]=relu(acc+b[d])
    bf16* Hp = (bf16*)Cout;
#pragma unroll
    for (int i = 0; i < 4; ++i) {
      const long drow = base_m + i * 16 + lq * 4;
      const f32x4 bv = *(const f32x4*)&bias[drow];
#pragma unroll
      for (int j = 0; j < 4; ++j) {
        const long colt = base_n + j * 16 + l16;
        float v0 = acc[i][j][0] + bv[0]; v0 = v0 > 0.f ? v0 : 0.f;
        float v1 = acc[i][j][1] + bv[1]; v1 = v1 > 0.f ? v1 : 0.f;
        float v2 = acc[i][j][2] + bv[2]; v2 = v2 > 0.f ? v2 : 0.f;
        float v3 = acc[i][j][3] + bv[3]; v3 = v3 > 0.f ? v3 : 0.f;
        us4 w = {bfb(v0), bfb(v1), bfb(v2), bfb(v3)};
        *(us4*)(Hp + colt * (long)ldc + drow) = w;
      }
    }
  } else {  // MODE 4
    // out[tok][d] = acc + bias[d] + resid[tok][d], fp32, float4 stores (nt:
    // 4 quad-lanes x 16B = full 64B line per row per instruction)
    float* Op = (float*)Cout;
#pragma unroll
    for (int i = 0; i < 4; ++i) {
      const long drow = base_m + i * 16 + lq * 4;
      const f32x4 bv = *(const f32x4*)&bias[drow];
#pragma unroll
      for (int j = 0; j < 4; ++j) {
        const long off = (base_n + j * 16 + l16) * (long)ldc + drow;
        const f32x4 rs = *(const f32x4*)&resid[off];
        f32x4 o;
        o[0] = acc[i][j][0] + bv[0] + rs[0];
        o[1] = acc[i][j][1] + bv[1] + rs[1];
        o[2] = acc[i][j][2] + bv[2] + rs[2];
        o[3] = acc[i][j][3] + bv[3] + rs[3];
        __builtin_nontemporal_store(o, (f32x4*)(Op + off));
      }
    }
  }
}

// ---------------------------------------------------------------------------
// Fused QKV projection: grid.z selects {Q, K, V}. z=0,1: A=y1 (rows=token),
// B=W, plain store to Qm/Km. z=2: OPERANDS SWAPPED (A=Wv rows=out_d, B=y1)
// so Vt[d][tok] is written with tok as the lane-contiguous dim (coalesced).
// ---------------------------------------------------------------------------
__global__ __launch_bounds__(256) void gemm_qkv(
    const bf16* __restrict__ Y,
    const bf16* __restrict__ Wq, const bf16* __restrict__ Wk,
    const bf16* __restrict__ Wv, bf16* __restrict__ Qm,
    bf16* __restrict__ Km, bf16* __restrict__ Vt) {
  __shared__ __align__(16) bf16 As[128 * 32];
  __shared__ __align__(16) bf16 Bs[128 * 32];

  const int z = blockIdx.z;
  const bf16* Ap = (z == 2) ? Wv : Y;
  const bf16* Bp = (z == 0) ? Wq : (z == 1) ? Wk : Y;

  const int tid  = threadIdx.x;
  const int wave = tid >> 6;
  const int lane = tid & 63;
  const int l16  = lane & 15;
  const int lq   = lane >> 4;
  const int wm   = wave >> 1;
  const int wn   = wave & 1;
  const long tileM = (z == 2) ? (long)blockIdx.x * 128 : (long)blockIdx.y * 128;
  const long tileN = (z == 2) ? (long)blockIdx.y * 128 : (long)blockIdx.x * 128;

  f32x4 acc[4][4] = {};

  const int c0 = wave * 128 + lane;
  const int c1 = c0 + 64;
  bf16* ldsA0 = &As[(wave * 128 + 0) * 8];
  bf16* ldsA1 = &As[(wave * 128 + 64) * 8];
  bf16* ldsB0 = &Bs[(wave * 128 + 0) * 8];
  bf16* ldsB1 = &Bs[(wave * 128 + 64) * 8];
  const long ar0 = (tileM + (c0 >> 2)) * (long)DDIM + (c0 & 3) * 8;
  const long ar1 = (tileM + (c1 >> 2)) * (long)DDIM + (c1 & 3) * 8;
  const long br0 = (tileN + (c0 >> 2)) * (long)DDIM + (c0 & 3) * 8;
  const long br1 = (tileN + (c1 >> 2)) * (long)DDIM + (c1 & 3) * 8;

  for (int k0 = 0; k0 < DDIM; k0 += 32) {
    gload16(Ap + ar0 + k0, ldsA0);
    gload16(Ap + ar1 + k0, ldsA1);
    gload16(Bp + br0 + k0, ldsB0);
    gload16(Bp + br1 + k0, ldsB1);
    __syncthreads();

    bf16x8 af[4], bf_[4];
#pragma unroll
    for (int i = 0; i < 4; ++i)
      af[i] = *(const bf16x8*)&As[(wm * 64 + i * 16 + l16) * 32 + lq * 8];
#pragma unroll
    for (int j = 0; j < 4; ++j)
      bf_[j] = *(const bf16x8*)&Bs[(wn * 64 + j * 16 + l16) * 32 + lq * 8];
#pragma unroll
    for (int i = 0; i < 4; ++i)
#pragma unroll
      for (int j = 0; j < 4; ++j)
        acc[i][j] = __builtin_amdgcn_mfma_f32_16x16x32_bf16(af[i], bf_[j],
                                                            acc[i][j], 0, 0, 0);
    __syncthreads();
  }

  const long base_m = tileM + wm * 64;
  const long base_n = tileN + wn * 64;
  bf16* Cp = (z == 0) ? Qm : (z == 1) ? Km : Vt;
  const long ldo = (z < 2) ? (long)DDIM : (long)ROWS;
#pragma unroll
  for (int i = 0; i < 4; ++i)
#pragma unroll
    for (int j = 0; j < 4; ++j)
#pragma unroll
      for (int r = 0; r < 4; ++r) {
        const long row = base_m + i * 16 + lq * 4 + r;
        const long col = base_n + j * 16 + l16;
        Cp[row * ldo + col] = __float2bfloat16(acc[i][j][r]);
      }
}

// ---------------------------------------------------------------------------
// LayerNorm (faithful to buggy reference): y = (x - mu/sqrt(var)) * g + b,
// var unbiased (ddof=1). One block (256 thr) per 768-element row. Out bf16.
// Optionally zeroes Lzero[row] (the attention row-sum accumulator).
// ---------------------------------------------------------------------------
template <typename T>
__global__ __launch_bounds__(256) void ln_kernel(
    const T* __restrict__ in, const float* __restrict__ g,
    const float* __restrict__ beta, bf16* __restrict__ out,
    float* __restrict__ Lzero) {
  const long row = blockIdx.x;
  if (Lzero != nullptr && threadIdx.x == 0) Lzero[row] = 0.f;
  const T* xr = in + row * DDIM;
  const int t = threadIdx.x;
  float v0 = to_f(xr[t]), v1 = to_f(xr[t + 256]), v2 = to_f(xr[t + 512]);
  float s = v0 + v1 + v2;
  float q = v0 * v0 + v1 * v1 + v2 * v2;
#pragma unroll
  for (int o = 32; o; o >>= 1) {
    s += __shfl_down(s, o);
    q += __shfl_down(q, o);
  }
  __shared__ float sb[4], qb[4];
  if ((t & 63) == 0) { sb[t >> 6] = s; qb[t >> 6] = q; }
  __syncthreads();
  const float S = sb[0] + sb[1] + sb[2] + sb[3];
  const float Q = qb[0] + qb[1] + qb[2] + qb[3];
  const float mu  = S * (1.0f / 768.0f);
  const float var = (Q - 768.0f * mu * mu) * (1.0f / 767.0f);
  const float sub = mu / sqrtf(var);
  bf16* orow = out + row * DDIM;
  orow[t]       = __float2bfloat16((v0 - sub) * g[t]       + beta[t]);
  orow[t + 256] = __float2bfloat16((v1 - sub) * g[t + 256] + beta[t + 256]);
  orow[t + 512] = __float2bfloat16((v2 - sub) * g[t + 512] + beta[t + 512]);
}

// ---------------------------------------------------------------------------
// Weight prep: z=0..2 transpose+cast wq/wk/wv (K x N -> N x K bf16),
// z=3..4 straight cast fc1_w/fc2_w (already N x K).
// block (32,8), grid (24,24,5)
// ---------------------------------------------------------------------------
__global__ void prep_weights(const float* __restrict__ wq,
                             const float* __restrict__ wk,
                             const float* __restrict__ wv,
                             const float* __restrict__ f1,
                             const float* __restrict__ f2,
                             bf16* wqt, bf16* wkt, bf16* wvt, bf16* f1b,
                             bf16* f2b) {
  __shared__ float tile[32][33];
  const float* src;
  bf16* dst;
  bool tr = true;
  switch (blockIdx.z) {
    case 0: src = wq; dst = wqt; break;
    case 1: src = wk; dst = wkt; break;
    case 2: src = wv; dst = wvt; break;
    case 3: src = f1; dst = f1b; tr = false; break;
    default: src = f2; dst = f2b; tr = false; break;
  }
  const int tx = threadIdx.x, ty = threadIdx.y;
  const int x = blockIdx.x * 32 + tx;
  const int y = blockIdx.y * 32 + ty;
  if (tr) {
#pragma unroll
    for (int r = 0; r < 4; ++r) tile[ty + 8 * r][tx] = src[(y + 8 * r) * DDIM + x];
    __syncthreads();
    const int ox = blockIdx.y * 32 + tx;
    const int oy = blockIdx.x * 32 + ty;
#pragma unroll
    for (int r = 0; r < 4; ++r)
      dst[(oy + 8 * r) * DDIM + ox] = __float2bfloat16(tile[tx][ty + 8 * r]);
  } else {
#pragma unroll
    for (int r = 0; r < 4; ++r)
      dst[(y + 8 * r) * DDIM + x] = __float2bfloat16(src[(y + 8 * r) * DDIM + x]);
  }
}

// ---------------------------------------------------------------------------
extern "C" void kernel_launch(void* const* d_in, const int* in_sizes, int n_in,
                              void* d_out, int out_size, void* d_ws,
                              size_t ws_size, hipStream_t stream) {
  const float* x     = (const float*)d_in[0];
  const float* ln1_g = (const float*)d_in[1];
  const float* ln1_b = (const float*)d_in[2];
  const float* wq    = (const float*)d_in[3];
  const float* wk    = (const float*)d_in[4];
  const float* wv    = (const float*)d_in[5];
  const float* ln2_g = (const float*)d_in[6];
  const float* ln2_b = (const float*)d_in[7];
  const float* f1w   = (const float*)d_in[8];
  const float* f1bias= (const float*)d_in[9];
  const float* f2w   = (const float*)d_in[10];
  const float* f2bias= (const float*)d_in[11];
  float* out = (float*)d_out;

  char* ws = (char*)d_ws;
  size_t off = 0;
  auto take = [&](size_t bytes) -> char* {
    char* p = ws + off;
    off += (bytes + 255) & ~(size_t)255;
    return p;
  };
  const size_t WB = (size_t)DDIM * DDIM * sizeof(bf16);   // 1.18 MB
  const size_t MB = (size_t)ROWS * DDIM * sizeof(bf16);   // 25.2 MB
  bf16* wqt = (bf16*)take(WB);
  bf16* wkt = (bf16*)take(WB);
  bf16* wvt = (bf16*)take(WB);
  bf16* f1b = (bf16*)take(WB);
  bf16* f2b = (bf16*)take(WB);
  float* Lsum = (float*)take((size_t)ROWS * sizeof(float));  // softmax row sums
  bf16* y1  = (bf16*)take(MB);
  bf16* Qm  = (bf16*)take(MB);
  bf16* Km  = (bf16*)take(MB);
  bf16* Vt  = (bf16*)take(MB);                              // V^T: 768 x 16384
  bf16* Sb  = (bf16*)take((size_t)NB * TT * TT * sizeof(bf16));  // 134 MB (P)
  // buffer reuse (strictly sequential stream):
  bf16* O  = y1;  // attention output (y1 dead after QKV)
  bf16* y2 = Qm;  // LN2 output      (Q dead after QK^T)
  bf16* h  = Km;  // MLP hidden      (K dead after QK^T)

  prep_weights<<<dim3(24, 24, 5), dim3(32, 8), 0, stream>>>(
      wq, wk, wv, f1w, f2w, wqt, wkt, wvt, f1b, f2b);

  // LN1 also zeroes Lsum (must precede QK^T; ws is re-poisoned every call)
  ln_kernel<float><<<ROWS, 256, 0, stream>>>(x, ln1_g, ln1_b, y1, Lsum);

  // Fused QKV projections, 2304 blocks (z=2 operand-swapped for Vt)
  gemm_qkv<<<dim3(6, 128, 3), 256, 0, stream>>>(y1, wqt, wkt, wvt, Qm, Km, Vt);

  // scale folded with log2(e): P = exp2(log2e/sqrt(768) * K Q^T)
  const float scale2 = 0.03608439182435161f * 1.4426950408889634f;
  // SWAPPED: A=K (rows=k), B=Q (rows=q). P[q][k] + row sums -> Lsum.
  gemm_bt<5, 1, 32, 32><<<dim3(32 * 32 * NB), 256, 0, stream>>>(
      Km, DDIM, (long)TT * DDIM, Qm, DDIM, (long)TT * DDIM, Sb, TT,
      (long)TT * TT, DDIM, scale2, nullptr, nullptr, Lsum);

  // SWAPPED: A=Vt (rows=d, k-contig per batch via sA=TT), B=P (rows=q).
  // m-fastest swizzle: P q-tile pinned per XCD group, Vt d-tiles cycle.
  gemm_bt<6, 2, 32, 6><<<dim3(6 * 32 * NB), 256, 0, stream>>>(
      Vt, ROWS, (long)TT, Sb, TT, (long)TT * TT, O, DDIM, (long)TT * DDIM, TT,
      1.f, nullptr, nullptr, Lsum);

  ln_kernel<bf16><<<ROWS, 256, 0, stream>>>(O, ln2_g, ln2_b, y2, nullptr);

  // MLP, SWAPPED (A=weight rows=out_d, B=activation rows=token).
  // m-fastest swizzle: activation tile pinned in L2, weight tiles cycle.
  gemm_bt<3, 2, 128, 6><<<dim3(128 * 6), 256, 0, stream>>>(
      f1b, DDIM, 0, y2, DDIM, 0, h, DDIM, 0, DDIM, 1.f, f1bias, nullptr,
      nullptr);
  gemm_bt<4, 2, 128, 6><<<dim3(128 * 6), 256, 0, stream>>>(
      f2b, DDIM, 0, h, DDIM, 0, out, DDIM, 0, DDIM, 1.f, f2bias, x, nullptr);
}